// Round 4
// baseline (313.932 us; speedup 1.0000x reference)
//
#include <hip/hip_runtime.h>
#include <hip/hip_bf16.h>

typedef unsigned int uint;
typedef unsigned short ushort;
typedef __bf16 bf16;
typedef bf16 bf16x8 __attribute__((ext_vector_type(8)));
typedef float f32x4 __attribute__((ext_vector_type(4)));
typedef ushort ushort4v __attribute__((ext_vector_type(4)));

__device__ __forceinline__ float bf2f(ushort u) {
  union { uint u; float f; } v; v.u = ((uint)u) << 16; return v.f;
}
__device__ __forceinline__ ushort f2bf(float f) {
  union { float f; uint u; } v; v.f = f;
  uint u = v.u;
  uint r = (u + 0x7fffu + ((u >> 16) & 1u)) >> 16;
  return (ushort)r;
}

__device__ __forceinline__ void gl2lds16(const void* g, void* l) {
  __builtin_amdgcn_global_load_lds(
      (const __attribute__((address_space(1))) void*)g,
      (__attribute__((address_space(3))) void*)l, 16, 0, 0);
}

// ---------------------------------------------------------------------------
// LayerNorm row worker (512 cols), one wave per row, grid-stride.
// ---------------------------------------------------------------------------
__device__ __forceinline__ void ln_rows(
    int mode, int nrows, int blk, int nblk, int tid,
    const void* __restrict__ srcA, const void* __restrict__ srcB,
    const float* __restrict__ g, const float* __restrict__ b,
    void* __restrict__ dst)
{
  const int l = tid & 63;
  const int nw = nblk * 4;
  for (int row = blk * 4 + (tid >> 6); row < nrows; row += nw) {
    float x[8];
    if (mode <= 1) {
      const float* s;
      if (mode == 0) {
        s = (const float*)srcA + (size_t)row * 512;
      } else {
        int mm = row >> 9, fi = row & 511;
        s = (const float*)srcA + ((size_t)mm * 514 + 2 + fi) * 512;
      }
      float4 a0 = *(const float4*)(s + l * 4);
      float4 a1 = *(const float4*)(s + 256 + l * 4);
      x[0] = a0.x; x[1] = a0.y; x[2] = a0.z; x[3] = a0.w;
      x[4] = a1.x; x[5] = a1.y; x[6] = a1.z; x[7] = a1.w;
    } else if (mode == 2) {
      const ushort* s = (const ushort*)srcA + (size_t)row * 512;
      uint4 u = *(const uint4*)(s + l * 8);
      x[0] = bf2f((ushort)u.x); x[1] = bf2f((ushort)(u.x >> 16));
      x[2] = bf2f((ushort)u.y); x[3] = bf2f((ushort)(u.y >> 16));
      x[4] = bf2f((ushort)u.z); x[5] = bf2f((ushort)(u.z >> 16));
      x[6] = bf2f((ushort)u.w); x[7] = bf2f((ushort)(u.w >> 16));
    } else {
      const ushort* sa = (const ushort*)srcA + (size_t)row * 512;
      const ushort* sb = (const ushort*)srcB + (size_t)row * 512;
      uint4 ua = *(const uint4*)(sa + l * 8);
      uint4 ub = *(const uint4*)(sb + l * 8);
      x[0] = bf2f((ushort)ua.x) + bf2f((ushort)ub.x);
      x[1] = bf2f((ushort)(ua.x >> 16)) + bf2f((ushort)(ub.x >> 16));
      x[2] = bf2f((ushort)ua.y) + bf2f((ushort)ub.y);
      x[3] = bf2f((ushort)(ua.y >> 16)) + bf2f((ushort)(ub.y >> 16));
      x[4] = bf2f((ushort)ua.z) + bf2f((ushort)ub.z);
      x[5] = bf2f((ushort)(ua.z >> 16)) + bf2f((ushort)(ub.z >> 16));
      x[6] = bf2f((ushort)ua.w) + bf2f((ushort)ub.w);
      x[7] = bf2f((ushort)(ua.w >> 16)) + bf2f((ushort)(ub.w >> 16));
    }
    float sum = 0.f, sq = 0.f;
    #pragma unroll
    for (int j = 0; j < 8; ++j) { sum += x[j]; sq += x[j] * x[j]; }
    #pragma unroll
    for (int o = 1; o < 64; o <<= 1) {
      sum += __shfl_xor(sum, o);
      sq  += __shfl_xor(sq, o);
    }
    const float inv = 1.f / 512.f;
    float mu = sum * inv;
    float var = sq * inv - mu * mu;
    float rstd = rsqrtf(var + 1e-5f);

    float gv[8], bv[8];
    if (mode <= 1) {
      float4 g0 = *(const float4*)(g + l * 4);
      float4 g1 = *(const float4*)(g + 256 + l * 4);
      float4 b0 = *(const float4*)(b + l * 4);
      float4 b1 = *(const float4*)(b + 256 + l * 4);
      gv[0] = g0.x; gv[1] = g0.y; gv[2] = g0.z; gv[3] = g0.w;
      gv[4] = g1.x; gv[5] = g1.y; gv[6] = g1.z; gv[7] = g1.w;
      bv[0] = b0.x; bv[1] = b0.y; bv[2] = b0.z; bv[3] = b0.w;
      bv[4] = b1.x; bv[5] = b1.y; bv[6] = b1.z; bv[7] = b1.w;
    } else {
      float4 g0 = *(const float4*)(g + l * 8);
      float4 g1 = *(const float4*)(g + l * 8 + 4);
      float4 b0 = *(const float4*)(b + l * 8);
      float4 b1 = *(const float4*)(b + l * 8 + 4);
      gv[0] = g0.x; gv[1] = g0.y; gv[2] = g0.z; gv[3] = g0.w;
      gv[4] = g1.x; gv[5] = g1.y; gv[6] = g1.z; gv[7] = g1.w;
      bv[0] = b0.x; bv[1] = b0.y; bv[2] = b0.z; bv[3] = b0.w;
      bv[4] = b1.x; bv[5] = b1.y; bv[6] = b1.z; bv[7] = b1.w;
    }
    float y[8];
    #pragma unroll
    for (int j = 0; j < 8; ++j) y[j] = (x[j] - mu) * rstd * gv[j] + bv[j];

    if (mode <= 1) {
      ushort* d = (ushort*)dst + (size_t)row * 512;
      ushort4v p0, p1;
      #pragma unroll
      for (int j = 0; j < 4; ++j) { p0[j] = f2bf(y[j]); p1[j] = f2bf(y[4 + j]); }
      *(ushort4v*)(d + l * 4) = p0;
      *(ushort4v*)(d + 256 + l * 4) = p1;
    } else if (mode == 2) {
      ushort* d = (ushort*)dst + (size_t)row * 512;
      uint4 o;
      o.x = (uint)f2bf(y[0]) | ((uint)f2bf(y[1]) << 16);
      o.y = (uint)f2bf(y[2]) | ((uint)f2bf(y[3]) << 16);
      o.z = (uint)f2bf(y[4]) | ((uint)f2bf(y[5]) << 16);
      o.w = (uint)f2bf(y[6]) | ((uint)f2bf(y[7]) << 16);
      *(uint4*)(d + l * 8) = o;
    } else {
      float* d = (float*)dst + (size_t)row * 512;
      float4 o0, o1;
      o0.x = y[0]; o0.y = y[1]; o0.z = y[2]; o0.w = y[3];
      o1.x = y[4]; o1.y = y[5]; o1.z = y[6]; o1.w = y[7];
      *(float4*)(d + l * 8) = o0;
      *(float4*)(d + l * 8 + 4) = o1;
    }
  }
}

__global__ __launch_bounds__(256) void ln512v(
    int mode, int nrows,
    const void* __restrict__ srcA, const void* __restrict__ srcB,
    const float* __restrict__ g, const float* __restrict__ b,
    void* __restrict__ dst)
{
  ln_rows(mode, nrows, blockIdx.x, gridDim.x, threadIdx.x, srcA, srcB, g, b, dst);
}

// ---------------------------------------------------------------------------
// Preamble: blocks 0-639 cast 5 weights, 640-671 ln0 (video), 672+ ln1 (music)
// ---------------------------------------------------------------------------
struct PreArgs {
  const float* s0; const float* s1; const float* s2; const float* s3; const float* s4;
  ushort* d0; ushort* d1; ushort* d2; ushort* d3; ushort* d4;
  const float* video; const float* music;
  const float* g1; const float* b1;
  ushort* veln; ushort* mfln;
};
__global__ __launch_bounds__(256) void preamble(PreArgs a) {
  int bb = blockIdx.x;
  if (bb < 640) {
    int t = bb * 256 + threadIdx.x;
    int which = t >> 15;
    int e = (t & 32767) * 8;
    const float* s = which == 0 ? a.s0 : which == 1 ? a.s1 : which == 2 ? a.s2 : which == 3 ? a.s3 : a.s4;
    ushort*      d = which == 0 ? a.d0 : which == 1 ? a.d1 : which == 2 ? a.d2 : which == 3 ? a.d3 : a.d4;
    float4 v0 = *(const float4*)(s + e);
    float4 v1 = *(const float4*)(s + e + 4);
    uint4 o;
    o.x = (uint)f2bf(v0.x) | ((uint)f2bf(v0.y) << 16);
    o.y = (uint)f2bf(v0.z) | ((uint)f2bf(v0.w) << 16);
    o.z = (uint)f2bf(v1.x) | ((uint)f2bf(v1.y) << 16);
    o.w = (uint)f2bf(v1.z) | ((uint)f2bf(v1.w) << 16);
    *(uint4*)(d + e) = o;
  } else if (bb < 672) {
    ln_rows(0, 128, bb - 640, 32, threadIdx.x, a.video, nullptr, a.g1, a.b1, a.veln);
  } else {
    ln_rows(1, 65536, bb - 672, 2048, threadIdx.x, a.music, nullptr, a.g1, a.b1, a.mfln);
  }
}

// ---------------------------------------------------------------------------
// Fused K+V (+Q) projection GEMM. BM=BN=128, BK=64, 4 waves (2x2 of 64x64).
// One staged A-tile feeds both Wk and Wv MFMA streams (64 MFMA per stage of
// 3 tiles vs 32 per 2 tiles unfused).
// grid (4, 513): by<512 -> A=mfln rows by*128, outputs K (row-major) and
//   Vt (transposed per-m). by==512 -> A=veln (128 rows), W=Wq, out Q*0.125.
// ---------------------------------------------------------------------------
__global__ __launch_bounds__(256) void gemm_kvq(
    const ushort* __restrict__ A, const ushort* __restrict__ Aq,
    const ushort* __restrict__ Wk, const ushort* __restrict__ Wv,
    const ushort* __restrict__ Wq,
    const float* __restrict__ bk, const float* __restrict__ bv,
    const float* __restrict__ bq,
    ushort* __restrict__ K, ushort* __restrict__ Vt, ushort* __restrict__ Q)
{
  __shared__ __align__(16) ushort As[128 * 64];
  __shared__ __align__(16) ushort Bks[128 * 64];
  __shared__ __align__(16) ushort Bvs[128 * 64];
  const int tid = threadIdx.x;
  const int w = tid >> 6, l = tid & 63;
  const int lg = l >> 4, lr = l & 15;
  const int wr = w >> 1, wc = w & 1;
  const bool isq = (blockIdx.y == 512);
  const int row0 = isq ? 0 : blockIdx.y * 128;
  const int col0 = blockIdx.x * 128;
  const ushort* Ap  = isq ? Aq : A;
  const ushort* Wkp = isq ? Wq : Wk;

  f32x4 kacc[4][4], vacc[4][4];
  #pragma unroll
  for (int i = 0; i < 4; i++)
    #pragma unroll
    for (int j = 0; j < 4; j++) {
      f32x4 z = {0.f,0.f,0.f,0.f};
      kacc[i][j] = z; vacc[i][j] = z;
    }

  for (int kk = 0; kk < 8; ++kk) {
    #pragma unroll
    for (int c2 = 0; c2 < 4; ++c2) {
      int c = c2 * 256 + tid;
      int r = c >> 3, j = c & 7;
      int ksrc = kk * 64 + ((j ^ (r & 7)) * 8);
      int dst = (c2 * 256 + w * 64) * 8;
      gl2lds16(Ap  + (size_t)(row0 + r) * 512 + ksrc, As  + dst);
      gl2lds16(Wkp + (size_t)(col0 + r) * 512 + ksrc, Bks + dst);
      if (!isq) gl2lds16(Wv + (size_t)(col0 + r) * 512 + ksrc, Bvs + dst);
    }
    __syncthreads();
    #pragma unroll
    for (int ks = 0; ks < 2; ++ks) {
      bf16x8 af[4], bkf[4];
      #pragma unroll
      for (int mi = 0; mi < 4; ++mi) {
        int r = wr * 64 + mi * 16 + lr;
        af[mi] = *(const bf16x8*)(As + r * 64 + ((ks * 32 + lg * 8) ^ ((r & 7) * 8)));
      }
      #pragma unroll
      for (int ni = 0; ni < 4; ++ni) {
        int r = wc * 64 + ni * 16 + lr;
        bkf[ni] = *(const bf16x8*)(Bks + r * 64 + ((ks * 32 + lg * 8) ^ ((r & 7) * 8)));
      }
      __builtin_amdgcn_s_setprio(1);
      #pragma unroll
      for (int mi = 0; mi < 4; ++mi)
        #pragma unroll
        for (int ni = 0; ni < 4; ++ni)
          kacc[mi][ni] = __builtin_amdgcn_mfma_f32_16x16x32_bf16(af[mi], bkf[ni], kacc[mi][ni], 0, 0, 0);
      __builtin_amdgcn_s_setprio(0);
      if (!isq) {
        bf16x8 bvf[4];
        #pragma unroll
        for (int ni = 0; ni < 4; ++ni) {
          int r = wc * 64 + ni * 16 + lr;
          bvf[ni] = *(const bf16x8*)(Bvs + r * 64 + ((ks * 32 + lg * 8) ^ ((r & 7) * 8)));
        }
        __builtin_amdgcn_s_setprio(1);
        #pragma unroll
        for (int mi = 0; mi < 4; ++mi)
          #pragma unroll
          for (int ni = 0; ni < 4; ++ni)
            vacc[mi][ni] = __builtin_amdgcn_mfma_f32_16x16x32_bf16(af[mi], bvf[ni], vacc[mi][ni], 0, 0, 0);
        __builtin_amdgcn_s_setprio(0);
      }
    }
    __syncthreads();
  }

  #pragma unroll
  for (int ni = 0; ni < 4; ++ni) {
    int cg = col0 + wc * 64 + ni * 16 + lr;
    float bkc = isq ? bq[cg] : bk[cg];
    float bvc = isq ? 0.f : bv[cg];
    #pragma unroll
    for (int mi = 0; mi < 4; ++mi) {
      int rg0 = row0 + wr * 64 + mi * 16 + lg * 4;
      if (isq) {
        #pragma unroll
        for (int e = 0; e < 4; ++e)
          Q[(size_t)(rg0 + e) * 512 + cg] = f2bf((kacc[mi][ni][e] + bkc) * 0.125f);
      } else {
        #pragma unroll
        for (int e = 0; e < 4; ++e)
          K[(size_t)(rg0 + e) * 512 + cg] = f2bf(kacc[mi][ni][e] + bkc);
        int m = rg0 >> 9, fi = rg0 & 511;
        ushort4v pk;
        #pragma unroll
        for (int e = 0; e < 4; ++e) pk[e] = f2bf(vacc[mi][ni][e] + bvc);
        *(ushort4v*)(Vt + (size_t)(m * 512 + cg) * 512 + fi) = pk;
      }
    }
  }
}

// ---------------------------------------------------------------------------
// GEMM for Wo/Wl: BM=128, BN=256, 8 waves. XCD swizzle when nwg%8==0.
// ---------------------------------------------------------------------------
__global__ __launch_bounds__(512) void gemm512x(
    const ushort* __restrict__ A, const ushort* __restrict__ W,
    const float* __restrict__ bias, ushort* __restrict__ C,
    float scale, int vt_mode)
{
  __shared__ __align__(16) ushort As[128 * 64];
  __shared__ __align__(16) ushort Bs[256 * 64];
  const int tid = threadIdx.x;
  const int w = tid >> 6, l = tid & 63;
  const int lg = l >> 4, lr = l & 15;
  const int wr = w >> 2, wc = w & 3;

  int nwg = gridDim.x * gridDim.y;
  int bid = blockIdx.y * gridDim.x + blockIdx.x;
  if ((nwg & 7) == 0) bid = (bid & 7) * (nwg >> 3) + (bid >> 3);
  const int bx = bid % gridDim.x, by = bid / gridDim.x;
  const int row0 = by * 128, col0 = bx * 256;

  f32x4 acc[4][4];
  #pragma unroll
  for (int i = 0; i < 4; i++)
    #pragma unroll
    for (int j = 0; j < 4; j++) { f32x4 z = {0.f,0.f,0.f,0.f}; acc[i][j] = z; }

  for (int kk = 0; kk < 8; ++kk) {
    #pragma unroll
    for (int li = 0; li < 2; ++li) {
      int c = li * 512 + tid;
      int r = c >> 3, j = c & 7;
      gl2lds16(A + (size_t)(row0 + r) * 512 + kk * 64 + ((j ^ (r & 7)) * 8),
               As + (li * 512 + w * 64) * 8);
    }
    #pragma unroll
    for (int li = 0; li < 4; ++li) {
      int c = li * 512 + tid;
      int r = c >> 3, j = c & 7;
      gl2lds16(W + (size_t)(col0 + r) * 512 + kk * 64 + ((j ^ (r & 7)) * 8),
               Bs + (li * 512 + w * 64) * 8);
    }
    __syncthreads();
    #pragma unroll
    for (int ks = 0; ks < 2; ++ks) {
      bf16x8 af[4], bfr[4];
      #pragma unroll
      for (int mi = 0; mi < 4; ++mi) {
        int r = wr * 64 + mi * 16 + lr;
        af[mi] = *(const bf16x8*)(As + r * 64 + ((ks * 32 + lg * 8) ^ ((r & 7) * 8)));
      }
      #pragma unroll
      for (int ni = 0; ni < 4; ++ni) {
        int r = wc * 64 + ni * 16 + lr;
        bfr[ni] = *(const bf16x8*)(Bs + r * 64 + ((ks * 32 + lg * 8) ^ ((r & 7) * 8)));
      }
      __builtin_amdgcn_s_setprio(1);
      #pragma unroll
      for (int mi = 0; mi < 4; ++mi)
        #pragma unroll
        for (int ni = 0; ni < 4; ++ni)
          acc[mi][ni] = __builtin_amdgcn_mfma_f32_16x16x32_bf16(af[mi], bfr[ni], acc[mi][ni], 0, 0, 0);
      __builtin_amdgcn_s_setprio(0);
    }
    __syncthreads();
  }

  #pragma unroll
  for (int ni = 0; ni < 4; ++ni) {
    int cg = col0 + wc * 64 + ni * 16 + lr;
    float bc = bias[cg];
    #pragma unroll
    for (int mi = 0; mi < 4; ++mi) {
      int rg0 = row0 + wr * 64 + mi * 16 + lg * 4;
      if (!vt_mode) {
        #pragma unroll
        for (int e = 0; e < 4; ++e) {
          float v = (acc[mi][ni][e] + bc) * scale;
          C[(size_t)(rg0 + e) * 512 + cg] = f2bf(v);
        }
      } else {
        int m = rg0 >> 9, fi = rg0 & 511;
        ushort4v pk;
        #pragma unroll
        for (int e = 0; e < 4; ++e) pk[e] = f2bf((acc[mi][ni][e] + bc) * scale);
        *(ushort4v*)(C + (size_t)(m * 512 + cg) * 512 + fi) = pk;
      }
    }
  }
}

// ---------------------------------------------------------------------------
// Attention: one block per (m,h). 4 waves x 32 v-rows. Flash-style over f.
// ---------------------------------------------------------------------------
__global__ __launch_bounds__(256) void attn_kernel(
    const ushort* __restrict__ q, const ushort* __restrict__ k,
    const ushort* __restrict__ vt, const int* __restrict__ masks,
    ushort* __restrict__ attn)
{
  __shared__ __align__(16) ushort Qs[128 * 64];
  __shared__ __align__(16) ushort Ks[64 * 64];
  __shared__ __align__(16) ushort Vs[64 * 64];
  __shared__ __align__(16) ushort Ps[4][32 * 64];
  __shared__ float maskf[64];
  __shared__ float stats[4][32];

  const int tid = threadIdx.x;
  const int w = tid >> 6, l = tid & 63;
  const int lg = l >> 4, lr = l & 15;
  const int m = blockIdx.x >> 3, h = blockIdx.x & 7;

  const size_t kbase = (size_t)(m * 512) * 512 + h * 64;
  const size_t vbase = (size_t)(m * 512 + h * 64) * 512;

  #pragma unroll
  for (int c2 = 0; c2 < 4; ++c2) {
    int c = c2 * 256 + tid;
    int r = c >> 3, j = c & 7;
    gl2lds16(q + (size_t)r * 512 + h * 64 + ((j * 8) ^ ((r & 7) * 8)),
             Qs + (c2 * 256 + w * 64) * 8);
  }

  f32x4 acc[2][4];
  #pragma unroll
  for (int i = 0; i < 2; i++)
    #pragma unroll
    for (int j = 0; j < 4; j++) { f32x4 z = {0.f,0.f,0.f,0.f}; acc[i][j] = z; }
  float m_run[2] = {-INFINITY, -INFINITY};
  float l_run[2] = {0.f, 0.f};
  bf16x8 qf[2][2];

  for (int it = 0; it < 8; ++it) {
    const int f0 = it * 64;
    #pragma unroll
    for (int c2 = 0; c2 < 2; ++c2) {
      int c = c2 * 256 + tid;
      int r = c >> 3, j = c & 7;
      int off = (j * 8) ^ ((r & 7) * 8);
      gl2lds16(k + kbase + (size_t)(f0 + r) * 512 + off, Ks + (c2 * 256 + w * 64) * 8);
      gl2lds16(vt + vbase + (size_t)r * 512 + f0 + off, Vs + (c2 * 256 + w * 64) * 8);
    }
    if (tid < 64) maskf[tid] = masks[m * 512 + f0 + tid] ? 0.f : -1e30f;
    __syncthreads();

    if (it == 0) {
      #pragma unroll
      for (int nv = 0; nv < 2; ++nv)
        #pragma unroll
        for (int k2 = 0; k2 < 2; ++k2) {
          int v = w * 32 + nv * 16 + lr;
          qf[nv][k2] = *(const bf16x8*)(Qs + v * 64 + ((k2 * 32 + lg * 8) ^ ((v & 7) * 8)));
        }
    }

    f32x4 s[4][2];
    #pragma unroll
    for (int mi = 0; mi < 4; mi++)
      #pragma unroll
      for (int nv = 0; nv < 2; nv++) { f32x4 z = {0.f,0.f,0.f,0.f}; s[mi][nv] = z; }
    #pragma unroll
    for (int k2 = 0; k2 < 2; ++k2) {
      bf16x8 kf[4];
      #pragma unroll
      for (int mi = 0; mi < 4; ++mi) {
        int f = mi * 16 + lr;
        kf[mi] = *(const bf16x8*)(Ks + f * 64 + ((k2 * 32 + lg * 8) ^ ((f & 7) * 8)));
      }
      __builtin_amdgcn_s_setprio(1);
      #pragma unroll
      for (int mi = 0; mi < 4; ++mi)
        #pragma unroll
        for (int nv = 0; nv < 2; ++nv)
          s[mi][nv] = __builtin_amdgcn_mfma_f32_16x16x32_bf16(kf[mi], qf[nv][k2], s[mi][nv], 0, 0, 0);
      __builtin_amdgcn_s_setprio(0);
    }

    float mk[4][4];
    #pragma unroll
    for (int mi = 0; mi < 4; mi++)
      #pragma unroll
      for (int e = 0; e < 4; e++) mk[mi][e] = maskf[mi * 16 + lg * 4 + e];

    #pragma unroll
    for (int nv = 0; nv < 2; ++nv) {
      float cmax = -INFINITY;
      #pragma unroll
      for (int mi = 0; mi < 4; mi++)
        #pragma unroll
        for (int e = 0; e < 4; e++) {
          s[mi][nv][e] += mk[mi][e];
          cmax = fmaxf(cmax, s[mi][nv][e]);
        }
      cmax = fmaxf(cmax, __shfl_xor(cmax, 16));
      cmax = fmaxf(cmax, __shfl_xor(cmax, 32));
      float mnew = fmaxf(m_run[nv], cmax);
      float sc = __expf(m_run[nv] - mnew);
      float csum = 0.f;
      int vloc = nv * 16 + lr;
      #pragma unroll
      for (int mi = 0; mi < 4; mi++) {
        ushort4v pk;
        #pragma unroll
        for (int e = 0; e < 4; e++) {
          float p = __expf(s[mi][nv][e] - mnew);
          csum += p;
          pk[e] = f2bf(p);
        }
        int f = mi * 16 + lg * 4;
        *(ushort4v*)(&Ps[w][vloc * 64 + (f ^ ((vloc & 7) * 8))]) = pk;
      }
      csum += __shfl_xor(csum, 16);
      csum += __shfl_xor(csum, 32);
      l_run[nv] = l_run[nv] * sc + csum;
      m_run[nv] = mnew;
      if (lg == 0) stats[w][vloc] = sc;
    }

    #pragma unroll
    for (int mi2 = 0; mi2 < 2; ++mi2)
      #pragma unroll
      for (int e = 0; e < 4; ++e) {
        float sc = stats[w][mi2 * 16 + lg * 4 + e];
        #pragma unroll
        for (int nd = 0; nd < 4; ++nd) acc[mi2][nd][e] *= sc;
      }

    #pragma unroll
    for (int k2 = 0; k2 < 2; ++k2) {
      bf16x8 pf[2], vf[4];
      #pragma unroll
      for (int mi2 = 0; mi2 < 2; ++mi2) {
        int vloc = mi2 * 16 + lr;
        pf[mi2] = *(const bf16x8*)(&Ps[w][vloc * 64 + ((k2 * 32 + lg * 8) ^ ((vloc & 7) * 8))]);
      }
      #pragma unroll
      for (int nd = 0; nd < 4; ++nd) {
        int d = nd * 16 + lr;
        vf[nd] = *(const bf16x8*)(Vs + d * 64 + ((k2 * 32 + lg * 8) ^ ((d & 7) * 8)));
      }
      __builtin_amdgcn_s_setprio(1);
      #pragma unroll
      for (int mi2 = 0; mi2 < 2; ++mi2)
        #pragma unroll
        for (int nd = 0; nd < 4; ++nd)
          acc[mi2][nd] = __builtin_amdgcn_mfma_f32_16x16x32_bf16(pf[mi2], vf[nd], acc[mi2][nd], 0, 0, 0);
      __builtin_amdgcn_s_setprio(0);
    }
    __syncthreads();
  }

  #pragma unroll
  for (int nv = 0; nv < 2; ++nv)
    if (lg == 0) stats[w][nv * 16 + lr] = 1.f / l_run[nv];
  #pragma unroll
  for (int mi2 = 0; mi2 < 2; ++mi2)
    #pragma unroll
    for (int e = 0; e < 4; ++e) {
      float invl = stats[w][mi2 * 16 + lg * 4 + e];
      int vg = w * 32 + mi2 * 16 + lg * 4 + e;
      #pragma unroll
      for (int nd = 0; nd < 4; ++nd) {
        int d = nd * 16 + lr;
        attn[(size_t)(vg * 128 + m) * 512 + h * 64 + d] = f2bf(acc[mi2][nd][e] * invl);
      }
    }
}

// ---------------------------------------------------------------------------
extern "C" void kernel_launch(void* const* d_in, const int* in_sizes, int n_in,
                              void* d_out, int out_size, void* d_ws, size_t ws_size,
                              hipStream_t stream) {
  const float* video = (const float*)d_in[0];
  const float* music = (const float*)d_in[1];
  const int*   masks = (const int*)d_in[2];
  const float* Wq = (const float*)d_in[3];
  const float* Wk = (const float*)d_in[4];
  const float* Wv = (const float*)d_in[5];
  const float* Wo = (const float*)d_in[6];
  const float* Wl = (const float*)d_in[7];
  const float* bq = (const float*)d_in[8];
  const float* bk = (const float*)d_in[9];
  const float* bv = (const float*)d_in[10];
  const float* bo = (const float*)d_in[11];
  const float* bl = (const float*)d_in[12];
  const float* g1 = (const float*)d_in[13];
  const float* g2 = (const float*)d_in[14];
  const float* g3 = (const float*)d_in[15];
  const float* b1 = (const float*)d_in[16];
  const float* b2 = (const float*)d_in[17];
  const float* b3 = (const float*)d_in[18];

  char* ws = (char*)d_ws;
  ushort* mfln = (ushort*)(ws);                    // 65536x512 bf16
  ushort* kbuf = (ushort*)(ws + 67108864);         // 65536x512 bf16
  ushort* vtb  = (ushort*)(ws + 134217728);        // 65536x512 bf16 (transposed per m)
  ushort* attn = (ushort*)(ws + 201326592);        // 16384x512 bf16
  ushort* c1   = (ushort*)(ws + 218103808);        // 16384x512 bf16
  ushort* xbuf = (ushort*)(ws + 234881024);        // 16384x512 bf16
  ushort* veln = (ushort*)(ws + 251658240);        // 128x512 bf16
  ushort* qbuf = (ushort*)(ws + 251789312);        // 128x512 bf16
  ushort* wqb  = (ushort*)(ws + 251920384);
  ushort* wkb  = wqb + 262144;
  ushort* wvb  = wkb + 262144;
  ushort* wob  = wvb + 262144;
  ushort* wlb  = wob + 262144;

  PreArgs pa = {Wq, Wk, Wv, Wo, Wl, wqb, wkb, wvb, wob, wlb,
                video, music, g1, b1, veln, mfln};
  preamble<<<2720, 256, 0, stream>>>(pa);

  gemm_kvq<<<dim3(4, 513), 256, 0, stream>>>(
      mfln, veln, wkb, wvb, wqb, bk, bv, bq, kbuf, vtb, qbuf);

  attn_kernel<<<1024, 256, 0, stream>>>(qbuf, kbuf, vtb, masks, attn);

  gemm512x<<<dim3(2, 128), 512, 0, stream>>>(attn, wob, bo, c1, 1.f, 0);
  ln512v<<<2048, 256, 0, stream>>>(2, 16384, c1, nullptr, g2, b2, xbuf);
  gemm512x<<<dim3(2, 128), 512, 0, stream>>>(xbuf, wlb, bl, c1, 1.f, 0);
  ln512v<<<2048, 256, 0, stream>>>(3, 16384, xbuf, c1, g3, b3, d_out);
}

// Round 5
// 282.303 us; speedup vs baseline: 1.1120x; 1.1120x over previous
//
#include <hip/hip_runtime.h>
#include <hip/hip_bf16.h>

typedef unsigned int uint;
typedef unsigned short ushort;
typedef __bf16 bf16;
typedef bf16 bf16x8 __attribute__((ext_vector_type(8)));
typedef float f32x4 __attribute__((ext_vector_type(4)));
typedef ushort ushort4v __attribute__((ext_vector_type(4)));

__device__ __forceinline__ float bf2f(ushort u) {
  union { uint u; float f; } v; v.u = ((uint)u) << 16; return v.f;
}
__device__ __forceinline__ ushort f2bf(float f) {
  union { float f; uint u; } v; v.f = f;
  uint u = v.u;
  uint r = (u + 0x7fffu + ((u >> 16) & 1u)) >> 16;
  return (ushort)r;
}

__device__ __forceinline__ void gl2lds16(const void* g, void* l) {
  __builtin_amdgcn_global_load_lds(
      (const __attribute__((address_space(1))) void*)g,
      (__attribute__((address_space(3))) void*)l, 16, 0, 0);
}

// ---------------------------------------------------------------------------
// LayerNorm row worker (512 cols), one wave per row, grid-stride.
// ---------------------------------------------------------------------------
__device__ __forceinline__ void ln_rows(
    int mode, int nrows, int blk, int nblk, int tid,
    const void* __restrict__ srcA, const void* __restrict__ srcB,
    const float* __restrict__ g, const float* __restrict__ b,
    void* __restrict__ dst)
{
  const int l = tid & 63;
  const int nw = nblk * 4;
  for (int row = blk * 4 + (tid >> 6); row < nrows; row += nw) {
    float x[8];
    if (mode <= 1) {
      const float* s;
      if (mode == 0) {
        s = (const float*)srcA + (size_t)row * 512;
      } else {
        int mm = row >> 9, fi = row & 511;
        s = (const float*)srcA + ((size_t)mm * 514 + 2 + fi) * 512;
      }
      float4 a0 = *(const float4*)(s + l * 4);
      float4 a1 = *(const float4*)(s + 256 + l * 4);
      x[0] = a0.x; x[1] = a0.y; x[2] = a0.z; x[3] = a0.w;
      x[4] = a1.x; x[5] = a1.y; x[6] = a1.z; x[7] = a1.w;
    } else if (mode == 2) {
      const ushort* s = (const ushort*)srcA + (size_t)row * 512;
      uint4 u = *(const uint4*)(s + l * 8);
      x[0] = bf2f((ushort)u.x); x[1] = bf2f((ushort)(u.x >> 16));
      x[2] = bf2f((ushort)u.y); x[3] = bf2f((ushort)(u.y >> 16));
      x[4] = bf2f((ushort)u.z); x[5] = bf2f((ushort)(u.z >> 16));
      x[6] = bf2f((ushort)u.w); x[7] = bf2f((ushort)(u.w >> 16));
    } else {
      const ushort* sa = (const ushort*)srcA + (size_t)row * 512;
      const ushort* sb = (const ushort*)srcB + (size_t)row * 512;
      uint4 ua = *(const uint4*)(sa + l * 8);
      uint4 ub = *(const uint4*)(sb + l * 8);
      x[0] = bf2f((ushort)ua.x) + bf2f((ushort)ub.x);
      x[1] = bf2f((ushort)(ua.x >> 16)) + bf2f((ushort)(ub.x >> 16));
      x[2] = bf2f((ushort)ua.y) + bf2f((ushort)ub.y);
      x[3] = bf2f((ushort)(ua.y >> 16)) + bf2f((ushort)(ub.y >> 16));
      x[4] = bf2f((ushort)ua.z) + bf2f((ushort)ub.z);
      x[5] = bf2f((ushort)(ua.z >> 16)) + bf2f((ushort)(ub.z >> 16));
      x[6] = bf2f((ushort)ua.w) + bf2f((ushort)ub.w);
      x[7] = bf2f((ushort)(ua.w >> 16)) + bf2f((ushort)(ub.w >> 16));
    }
    float sum = 0.f, sq = 0.f;
    #pragma unroll
    for (int j = 0; j < 8; ++j) { sum += x[j]; sq += x[j] * x[j]; }
    #pragma unroll
    for (int o = 1; o < 64; o <<= 1) {
      sum += __shfl_xor(sum, o);
      sq  += __shfl_xor(sq, o);
    }
    const float inv = 1.f / 512.f;
    float mu = sum * inv;
    float var = sq * inv - mu * mu;
    float rstd = rsqrtf(var + 1e-5f);

    float gv[8], bv[8];
    if (mode <= 1) {
      float4 g0 = *(const float4*)(g + l * 4);
      float4 g1 = *(const float4*)(g + 256 + l * 4);
      float4 b0 = *(const float4*)(b + l * 4);
      float4 b1 = *(const float4*)(b + 256 + l * 4);
      gv[0] = g0.x; gv[1] = g0.y; gv[2] = g0.z; gv[3] = g0.w;
      gv[4] = g1.x; gv[5] = g1.y; gv[6] = g1.z; gv[7] = g1.w;
      bv[0] = b0.x; bv[1] = b0.y; bv[2] = b0.z; bv[3] = b0.w;
      bv[4] = b1.x; bv[5] = b1.y; bv[6] = b1.z; bv[7] = b1.w;
    } else {
      float4 g0 = *(const float4*)(g + l * 8);
      float4 g1 = *(const float4*)(g + l * 8 + 4);
      float4 b0 = *(const float4*)(b + l * 8);
      float4 b1 = *(const float4*)(b + l * 8 + 4);
      gv[0] = g0.x; gv[1] = g0.y; gv[2] = g0.z; gv[3] = g0.w;
      gv[4] = g1.x; gv[5] = g1.y; gv[6] = g1.z; gv[7] = g1.w;
      bv[0] = b0.x; bv[1] = b0.y; bv[2] = b0.z; bv[3] = b0.w;
      bv[4] = b1.x; bv[5] = b1.y; bv[6] = b1.z; bv[7] = b1.w;
    }
    float y[8];
    #pragma unroll
    for (int j = 0; j < 8; ++j) y[j] = (x[j] - mu) * rstd * gv[j] + bv[j];

    if (mode <= 1) {
      ushort* d = (ushort*)dst + (size_t)row * 512;
      ushort4v p0, p1;
      #pragma unroll
      for (int j = 0; j < 4; ++j) { p0[j] = f2bf(y[j]); p1[j] = f2bf(y[4 + j]); }
      *(ushort4v*)(d + l * 4) = p0;
      *(ushort4v*)(d + 256 + l * 4) = p1;
    } else if (mode == 2) {
      ushort* d = (ushort*)dst + (size_t)row * 512;
      uint4 o;
      o.x = (uint)f2bf(y[0]) | ((uint)f2bf(y[1]) << 16);
      o.y = (uint)f2bf(y[2]) | ((uint)f2bf(y[3]) << 16);
      o.z = (uint)f2bf(y[4]) | ((uint)f2bf(y[5]) << 16);
      o.w = (uint)f2bf(y[6]) | ((uint)f2bf(y[7]) << 16);
      *(uint4*)(d + l * 8) = o;
    } else {
      float* d = (float*)dst + (size_t)row * 512;
      float4 o0, o1;
      o0.x = y[0]; o0.y = y[1]; o0.z = y[2]; o0.w = y[3];
      o1.x = y[4]; o1.y = y[5]; o1.z = y[6]; o1.w = y[7];
      *(float4*)(d + l * 8) = o0;
      *(float4*)(d + l * 8 + 4) = o1;
    }
  }
}

__global__ __launch_bounds__(256) void ln512v(
    int mode, int nrows,
    const void* __restrict__ srcA, const void* __restrict__ srcB,
    const float* __restrict__ g, const float* __restrict__ b,
    void* __restrict__ dst)
{
  ln_rows(mode, nrows, blockIdx.x, gridDim.x, threadIdx.x, srcA, srcB, g, b, dst);
}

// ---------------------------------------------------------------------------
// Preamble: blocks 0-639 cast 5 weights, 640-671 ln0 (video), 672+ ln1 (music)
// ---------------------------------------------------------------------------
struct PreArgs {
  const float* s0; const float* s1; const float* s2; const float* s3; const float* s4;
  ushort* d0; ushort* d1; ushort* d2; ushort* d3; ushort* d4;
  const float* video; const float* music;
  const float* g1; const float* b1;
  ushort* veln; ushort* mfln;
};
__global__ __launch_bounds__(256) void preamble(PreArgs a) {
  int bb = blockIdx.x;
  if (bb < 640) {
    int t = bb * 256 + threadIdx.x;
    int which = t >> 15;
    int e = (t & 32767) * 8;
    const float* s = which == 0 ? a.s0 : which == 1 ? a.s1 : which == 2 ? a.s2 : which == 3 ? a.s3 : a.s4;
    ushort*      d = which == 0 ? a.d0 : which == 1 ? a.d1 : which == 2 ? a.d2 : which == 3 ? a.d3 : a.d4;
    float4 v0 = *(const float4*)(s + e);
    float4 v1 = *(const float4*)(s + e + 4);
    uint4 o;
    o.x = (uint)f2bf(v0.x) | ((uint)f2bf(v0.y) << 16);
    o.y = (uint)f2bf(v0.z) | ((uint)f2bf(v0.w) << 16);
    o.z = (uint)f2bf(v1.x) | ((uint)f2bf(v1.y) << 16);
    o.w = (uint)f2bf(v1.z) | ((uint)f2bf(v1.w) << 16);
    *(uint4*)(d + e) = o;
  } else if (bb < 672) {
    ln_rows(0, 128, bb - 640, 32, threadIdx.x, a.video, nullptr, a.g1, a.b1, a.veln);
  } else {
    ln_rows(1, 65536, bb - 672, 2048, threadIdx.x, a.music, nullptr, a.g1, a.b1, a.mfln);
  }
}

// ---------------------------------------------------------------------------
// T3-minimum double-buffered GEMM. BM=BN=128, BK=64, 4 waves (2x2 of 64x64).
// LDS 64 KB (2 blocks/CU). Per K-step: issue next-tile global_load_lds FIRST,
// then ds_read+MFMA current tile, then ONE __syncthreads() (drains vmcnt).
// C[r,j] = (sum_d A[r,d]*W[j,d] + bias[j]) * scale
// vt_mode=0: C bf16 row-major (R x 512)
// vt_mode=1: C bf16 transposed per-m: C[(m*512 + j)*512 + fi], r=m*512+fi
// grid: (4, R/128). XCD bijective swizzle when nwg%8==0.
// ---------------------------------------------------------------------------
__global__ __launch_bounds__(256) void gemm_t3(
    const ushort* __restrict__ A, const ushort* __restrict__ W,
    const float* __restrict__ bias, ushort* __restrict__ C,
    float scale, int vt_mode)
{
  __shared__ __align__(16) ushort As[2][128 * 64];
  __shared__ __align__(16) ushort Bs[2][128 * 64];
  const int tid = threadIdx.x;
  const int w = tid >> 6, l = tid & 63;
  const int lg = l >> 4, lr = l & 15;
  const int wr = w >> 1, wc = w & 1;

  int nwg = gridDim.x * gridDim.y;
  int bid = blockIdx.y * gridDim.x + blockIdx.x;
  if ((nwg & 7) == 0) bid = (bid & 7) * (nwg >> 3) + (bid >> 3);
  const int bx = bid % gridDim.x, by = bid / gridDim.x;
  const int row0 = by * 128, col0 = bx * 128;

  f32x4 acc[4][4];
  #pragma unroll
  for (int i = 0; i < 4; i++)
    #pragma unroll
    for (int j = 0; j < 4; j++) { f32x4 z = {0.f,0.f,0.f,0.f}; acc[i][j] = z; }

  // per-thread staging offsets (pre-swizzled global source, linear LDS dest)
  size_t asrc[4], wsrc[4]; int ldst[4];
  #pragma unroll
  for (int c2 = 0; c2 < 4; ++c2) {
    int c = c2 * 256 + tid;
    int r = c >> 3, j = c & 7;
    int koff = (j ^ (r & 7)) * 8;
    asrc[c2] = (size_t)(row0 + r) * 512 + koff;
    wsrc[c2] = (size_t)(col0 + r) * 512 + koff;
    ldst[c2] = (c2 * 256 + w * 64) * 8;
  }

  auto stage = [&](int pb, int kk) {
    #pragma unroll
    for (int c2 = 0; c2 < 4; ++c2) {
      gl2lds16(A + asrc[c2] + kk * 64, &As[pb][ldst[c2]]);
      gl2lds16(W + wsrc[c2] + kk * 64, &Bs[pb][ldst[c2]]);
    }
  };
  auto compute = [&](int pb) {
    #pragma unroll
    for (int ks = 0; ks < 2; ++ks) {
      bf16x8 af[4], bfr[4];
      #pragma unroll
      for (int mi = 0; mi < 4; ++mi) {
        int r = wr * 64 + mi * 16 + lr;
        af[mi] = *(const bf16x8*)(&As[pb][r * 64 + ((ks * 32 + lg * 8) ^ ((r & 7) * 8))]);
      }
      #pragma unroll
      for (int ni = 0; ni < 4; ++ni) {
        int r = wc * 64 + ni * 16 + lr;
        bfr[ni] = *(const bf16x8*)(&Bs[pb][r * 64 + ((ks * 32 + lg * 8) ^ ((r & 7) * 8))]);
      }
      #pragma unroll
      for (int mi = 0; mi < 4; ++mi)
        #pragma unroll
        for (int ni = 0; ni < 4; ++ni)
          acc[mi][ni] = __builtin_amdgcn_mfma_f32_16x16x32_bf16(af[mi], bfr[ni], acc[mi][ni], 0, 0, 0);
    }
  };

  stage(0, 0);
  __syncthreads();
  int cur = 0;
  #pragma unroll
  for (int kk = 0; kk < 7; ++kk) {
    stage(cur ^ 1, kk + 1);   // issue next-tile loads (latency hides under MFMA)
    compute(cur);
    __syncthreads();          // drains vmcnt(0)+lgkmcnt(0), one barrier per K-step
    cur ^= 1;
  }
  compute(cur);

  #pragma unroll
  for (int ni = 0; ni < 4; ++ni) {
    int cg = col0 + wc * 64 + ni * 16 + lr;
    float bc = bias[cg];
    #pragma unroll
    for (int mi = 0; mi < 4; ++mi) {
      int rg0 = row0 + wr * 64 + mi * 16 + lg * 4;
      if (!vt_mode) {
        #pragma unroll
        for (int e = 0; e < 4; ++e) {
          float v = (acc[mi][ni][e] + bc) * scale;
          C[(size_t)(rg0 + e) * 512 + cg] = f2bf(v);
        }
      } else {
        int m = rg0 >> 9, fi = rg0 & 511;
        ushort4v pk;
        #pragma unroll
        for (int e = 0; e < 4; ++e) pk[e] = f2bf((acc[mi][ni][e] + bc) * scale);
        *(ushort4v*)(C + (size_t)(m * 512 + cg) * 512 + fi) = pk;
      }
    }
  }
}

// ---------------------------------------------------------------------------
// Attention: one block per (m,h). 4 waves x 32 v-rows. Flash-style over f.
// ---------------------------------------------------------------------------
__global__ __launch_bounds__(256) void attn_kernel(
    const ushort* __restrict__ q, const ushort* __restrict__ k,
    const ushort* __restrict__ vt, const int* __restrict__ masks,
    ushort* __restrict__ attn)
{
  __shared__ __align__(16) ushort Qs[128 * 64];
  __shared__ __align__(16) ushort Ks[64 * 64];
  __shared__ __align__(16) ushort Vs[64 * 64];
  __shared__ __align__(16) ushort Ps[4][32 * 64];
  __shared__ float maskf[64];
  __shared__ float stats[4][32];

  const int tid = threadIdx.x;
  const int w = tid >> 6, l = tid & 63;
  const int lg = l >> 4, lr = l & 15;
  const int m = blockIdx.x >> 3, h = blockIdx.x & 7;

  const size_t kbase = (size_t)(m * 512) * 512 + h * 64;
  const size_t vbase = (size_t)(m * 512 + h * 64) * 512;

  #pragma unroll
  for (int c2 = 0; c2 < 4; ++c2) {
    int c = c2 * 256 + tid;
    int r = c >> 3, j = c & 7;
    gl2lds16(q + (size_t)r * 512 + h * 64 + ((j * 8) ^ ((r & 7) * 8)),
             Qs + (c2 * 256 + w * 64) * 8);
  }

  f32x4 acc[2][4];
  #pragma unroll
  for (int i = 0; i < 2; i++)
    #pragma unroll
    for (int j = 0; j < 4; j++) { f32x4 z = {0.f,0.f,0.f,0.f}; acc[i][j] = z; }
  float m_run[2] = {-INFINITY, -INFINITY};
  float l_run[2] = {0.f, 0.f};
  bf16x8 qf[2][2];

  for (int it = 0; it < 8; ++it) {
    const int f0 = it * 64;
    #pragma unroll
    for (int c2 = 0; c2 < 2; ++c2) {
      int c = c2 * 256 + tid;
      int r = c >> 3, j = c & 7;
      int off = (j * 8) ^ ((r & 7) * 8);
      gl2lds16(k + kbase + (size_t)(f0 + r) * 512 + off, Ks + (c2 * 256 + w * 64) * 8);
      gl2lds16(vt + vbase + (size_t)r * 512 + f0 + off, Vs + (c2 * 256 + w * 64) * 8);
    }
    if (tid < 64) maskf[tid] = masks[m * 512 + f0 + tid] ? 0.f : -1e30f;
    __syncthreads();

    if (it == 0) {
      #pragma unroll
      for (int nv = 0; nv < 2; ++nv)
        #pragma unroll
        for (int k2 = 0; k2 < 2; ++k2) {
          int v = w * 32 + nv * 16 + lr;
          qf[nv][k2] = *(const bf16x8*)(Qs + v * 64 + ((k2 * 32 + lg * 8) ^ ((v & 7) * 8)));
        }
    }

    f32x4 s[4][2];
    #pragma unroll
    for (int mi = 0; mi < 4; mi++)
      #pragma unroll
      for (int nv = 0; nv < 2; nv++) { f32x4 z = {0.f,0.f,0.f,0.f}; s[mi][nv] = z; }
    #pragma unroll
    for (int k2 = 0; k2 < 2; ++k2) {
      bf16x8 kf[4];
      #pragma unroll
      for (int mi = 0; mi < 4; ++mi) {
        int f = mi * 16 + lr;
        kf[mi] = *(const bf16x8*)(Ks + f * 64 + ((k2 * 32 + lg * 8) ^ ((f & 7) * 8)));
      }
      __builtin_amdgcn_s_setprio(1);
      #pragma unroll
      for (int mi = 0; mi < 4; ++mi)
        #pragma unroll
        for (int nv = 0; nv < 2; ++nv)
          s[mi][nv] = __builtin_amdgcn_mfma_f32_16x16x32_bf16(kf[mi], qf[nv][k2], s[mi][nv], 0, 0, 0);
      __builtin_amdgcn_s_setprio(0);
    }

    float mk[4][4];
    #pragma unroll
    for (int mi = 0; mi < 4; mi++)
      #pragma unroll
      for (int e = 0; e < 4; e++) mk[mi][e] = maskf[mi * 16 + lg * 4 + e];

    #pragma unroll
    for (int nv = 0; nv < 2; ++nv) {
      float cmax = -INFINITY;
      #pragma unroll
      for (int mi = 0; mi < 4; mi++)
        #pragma unroll
        for (int e = 0; e < 4; e++) {
          s[mi][nv][e] += mk[mi][e];
          cmax = fmaxf(cmax, s[mi][nv][e]);
        }
      cmax = fmaxf(cmax, __shfl_xor(cmax, 16));
      cmax = fmaxf(cmax, __shfl_xor(cmax, 32));
      float mnew = fmaxf(m_run[nv], cmax);
      float sc = __expf(m_run[nv] - mnew);
      float csum = 0.f;
      int vloc = nv * 16 + lr;
      #pragma unroll
      for (int mi = 0; mi < 4; mi++) {
        ushort4v pk;
        #pragma unroll
        for (int e = 0; e < 4; e++) {
          float p = __expf(s[mi][nv][e] - mnew);
          csum += p;
          pk[e] = f2bf(p);
        }
        int f = mi * 16 + lg * 4;
        *(ushort4v*)(&Ps[w][vloc * 64 + (f ^ ((vloc & 7) * 8))]) = pk;
      }
      csum += __shfl_xor(csum, 16);
      csum += __shfl_xor(csum, 32);
      l_run[nv] = l_run[nv] * sc + csum;
      m_run[nv] = mnew;
      if (lg == 0) stats[w][vloc] = sc;
    }

    #pragma unroll
    for (int mi2 = 0; mi2 < 2; ++mi2)
      #pragma unroll
      for (int e = 0; e < 4; ++e) {
        float sc = stats[w][mi2 * 16 + lg * 4 + e];
        #pragma unroll
        for (int nd = 0; nd < 4; ++nd) acc[mi2][nd][e] *= sc;
      }

    #pragma unroll
    for (int k2 = 0; k2 < 2; ++k2) {
      bf16x8 pf[2], vf[4];
      #pragma unroll
      for (int mi2 = 0; mi2 < 2; ++mi2) {
        int vloc = mi2 * 16 + lr;
        pf[mi2] = *(const bf16x8*)(&Ps[w][vloc * 64 + ((k2 * 32 + lg * 8) ^ ((vloc & 7) * 8))]);
      }
      #pragma unroll
      for (int nd = 0; nd < 4; ++nd) {
        int d = nd * 16 + lr;
        vf[nd] = *(const bf16x8*)(Vs + d * 64 + ((k2 * 32 + lg * 8) ^ ((d & 7) * 8)));
      }
      __builtin_amdgcn_s_setprio(1);
      #pragma unroll
      for (int mi2 = 0; mi2 < 2; ++mi2)
        #pragma unroll
        for (int nd = 0; nd < 4; ++nd)
          acc[mi2][nd] = __builtin_amdgcn_mfma_f32_16x16x32_bf16(pf[mi2], vf[nd], acc[mi2][nd], 0, 0, 0);
      __builtin_amdgcn_s_setprio(0);
    }
    __syncthreads();
  }

  #pragma unroll
  for (int nv = 0; nv < 2; ++nv)
    if (lg == 0) stats[w][nv * 16 + lr] = 1.f / l_run[nv];
  #pragma unroll
  for (int mi2 = 0; mi2 < 2; ++mi2)
    #pragma unroll
    for (int e = 0; e < 4; ++e) {
      float invl = stats[w][mi2 * 16 + lg * 4 + e];
      int vg = w * 32 + mi2 * 16 + lg * 4 + e;
      #pragma unroll
      for (int nd = 0; nd < 4; ++nd) {
        int d = nd * 16 + lr;
        attn[(size_t)(vg * 128 + m) * 512 + h * 64 + d] = f2bf(acc[mi2][nd][e] * invl);
      }
    }
}

// ---------------------------------------------------------------------------
extern "C" void kernel_launch(void* const* d_in, const int* in_sizes, int n_in,
                              void* d_out, int out_size, void* d_ws, size_t ws_size,
                              hipStream_t stream) {
  const float* video = (const float*)d_in[0];
  const float* music = (const float*)d_in[1];
  const int*   masks = (const int*)d_in[2];
  const float* Wq = (const float*)d_in[3];
  const float* Wk = (const float*)d_in[4];
  const float* Wv = (const float*)d_in[5];
  const float* Wo = (const float*)d_in[6];
  const float* Wl = (const float*)d_in[7];
  const float* bq = (const float*)d_in[8];
  const float* bk = (const float*)d_in[9];
  const float* bv = (const float*)d_in[10];
  const float* bo = (const float*)d_in[11];
  const float* bl = (const float*)d_in[12];
  const float* g1 = (const float*)d_in[13];
  const float* g2 = (const float*)d_in[14];
  const float* g3 = (const float*)d_in[15];
  const float* b1 = (const float*)d_in[16];
  const float* b2 = (const float*)d_in[17];
  const float* b3 = (const float*)d_in[18];

  char* ws = (char*)d_ws;
  ushort* mfln = (ushort*)(ws);                    // 65536x512 bf16
  ushort* kbuf = (ushort*)(ws + 67108864);         // 65536x512 bf16
  ushort* vtb  = (ushort*)(ws + 134217728);        // 65536x512 bf16 (transposed per m)
  ushort* attn = (ushort*)(ws + 201326592);        // 16384x512 bf16
  ushort* c1   = (ushort*)(ws + 218103808);        // 16384x512 bf16
  ushort* xbuf = (ushort*)(ws + 234881024);        // 16384x512 bf16
  ushort* veln = (ushort*)(ws + 251658240);        // 128x512 bf16
  ushort* qbuf = (ushort*)(ws + 251789312);        // 128x512 bf16
  ushort* wqb  = (ushort*)(ws + 251920384);
  ushort* wkb  = wqb + 262144;
  ushort* wvb  = wkb + 262144;
  ushort* wob  = wvb + 262144;
  ushort* wlb  = wob + 262144;

  PreArgs pa = {Wq, Wk, Wv, Wo, Wl, wqb, wkb, wvb, wob, wlb,
                video, music, g1, b1, veln, mfln};
  preamble<<<2720, 256, 0, stream>>>(pa);

  gemm_t3<<<dim3(4, 1), 256, 0, stream>>>(veln, wqb, bq, qbuf, 0.125f, 0);
  gemm_t3<<<dim3(4, 512), 256, 0, stream>>>(mfln, wkb, bk, kbuf, 1.f, 0);
  gemm_t3<<<dim3(4, 512), 256, 0, stream>>>(mfln, wvb, bv, vtb, 1.f, 1);

  attn_kernel<<<1024, 256, 0, stream>>>(qbuf, kbuf, vtb, masks, attn);

  gemm_t3<<<dim3(4, 128), 256, 0, stream>>>(attn, wob, bo, c1, 1.f, 0);
  ln512v<<<2048, 256, 0, stream>>>(2, 16384, c1, nullptr, g2, b2, xbuf);
  gemm_t3<<<dim3(4, 128), 256, 0, stream>>>(xbuf, wlb, bl, c1, 1.f, 0);
  ln512v<<<2048, 256, 0, stream>>>(3, 16384, xbuf, c1, g3, b3, d_out);
}